// Round 1
// 213.718 us; speedup vs baseline: 1.5090x; 1.5090x over previous
//
#include <hip/hip_runtime.h>
#include <hip/hip_bf16.h>
#include <math.h>

#define S_LEN 1024
#define DH 64
#define NB 2
#define NHQ 32
#define NHKV 8
#define NHEADS (NB*NHKV)      // 16 kv-head planes
#define NTILE 16              // S/64
#define NTRI 136              // 16*17/2 lower-tri tiles
#define NEG_INF -1e30f

using bf16x8 = __attribute__((ext_vector_type(8))) __bf16;
using f32x4  = __attribute__((ext_vector_type(4))) float;

__device__ inline unsigned short f2bf(float f){
  unsigned int u = __float_as_uint(f);
  unsigned int r = (u + 0x7FFFu + ((u >> 16) & 1u)) >> 16;
  return (unsigned short)r;
}

// async global->LDS, 16B per lane, wave-uniform LDS base + lane*16
__device__ inline void gload16(const void* g, void* l){
  __builtin_amdgcn_global_load_lds(
      (const __attribute__((address_space(1))) void*)g,
      (__attribute__((address_space(3))) void*)l, 16, 0, 0);
}

// ---------------- kernel 1: normalize k rows -> kn (f32) + knb (bf16) ----------------
__global__ __launch_bounds__(256) void k_prep_kn(const float* __restrict__ k,
                                                 float* __restrict__ kn,
                                                 unsigned short* __restrict__ knb){
  int row  = blockIdx.x*4 + (threadIdx.x >> 6);   // among NHEADS*S
  int lane = threadIdx.x & 63;
  size_t idx = (size_t)row*DH + lane;
  float x = k[idx];
  float ss = x*x;
  #pragma unroll
  for (int off = 32; off > 0; off >>= 1) ss += __shfl_xor(ss, off);
  float r = x / (sqrtf(ss) + 1e-6f);
  kn[idx]  = r;
  knb[idx] = f2bf(r);
}

// ---------------- kernel 2: q->bf16, v->vT bf16, gates ----------------
__global__ __launch_bounds__(256) void k_prep_misc(const float* __restrict__ q,
                                                   const float* __restrict__ v,
                                                   const float* __restrict__ src,
                                                   const float* __restrict__ dest,
                                                   unsigned short* __restrict__ qb,
                                                   unsigned short* __restrict__ vT,
                                                   float* __restrict__ sg,
                                                   float* __restrict__ dg){
  int idx = blockIdx.x*256 + threadIdx.x;          // grid covers exactly B*H*S*D = 4M
  qb[idx] = f2bf(q[idx]);
  if (idx < NHEADS*DH*S_LEN){                      // 1M : vT[bh][dd][j] = v[bh][j][dd]
    int bh  = idx >> 16;
    int rem = idx & 65535;
    int dd  = rem >> 10;
    int j   = rem & 1023;
    vT[idx] = f2bf(v[((size_t)bh << 16) + (size_t)j*DH + dd]);
  }
  if (idx < 2*NHEADS*S_LEN){                       // 32768 : gates
    if (idx < NHEADS*S_LEN){
      float s = 1.f/(1.f + __expf(-dest[idx]));
      dg[idx] = (s > 0.f) ? exp2f(log2f(s)*(1.f/3.f)) : 0.f;
    } else {
      int i2 = idx - NHEADS*S_LEN;
      float s = 1.f/(1.f + __expf(-src[i2]));
      sg[i2] = (s > 0.f) ? exp2f(log2f(s)*(1.f/3.f)) : 0.f;
    }
  }
}

// ---------------- kernel 3: logdec tiles (fp32, lower-tri 64x64 tiles) ----------------
__global__ __launch_bounds__(256) void k_logdec(const float* __restrict__ kn,
                                                const float* __restrict__ dg,
                                                const float* __restrict__ sg,
                                                float* __restrict__ Dm){
  __shared__ float aI[64][66];
  __shared__ float bJ[64][66];
  int head = blockIdx.x / NTRI;
  int t    = blockIdx.x % NTRI;
  int ti = 0;
  while ((ti+1)*(ti+2)/2 <= t) ti++;
  int tj = t - ti*(ti+1)/2;
  int i0 = ti*64, j0 = tj*64;
  const float* base = kn + (size_t)head*S_LEN*DH;
  int tid = threadIdx.x;
  int dd0 = tid & 63, r0 = tid >> 6;
  #pragma unroll
  for (int p = 0; p < 16; ++p){
    int r = p*4 + r0;
    aI[r][dd0] = base[(size_t)(i0+r)*DH + dd0];
    bJ[r][dd0] = base[(size_t)(j0+r)*DH + dd0];
  }
  __syncthreads();
  int tx = tid & 15, ty = tid >> 4;
  float acc[4][4] = {};
  #pragma unroll 4
  for (int dd = 0; dd < 64; dd += 2){
    float2 av[4], bv[4];
    #pragma unroll
    for (int r = 0; r < 4; ++r){
      av[r] = *(const float2*)&aI[ty*4+r][dd];
      bv[r] = *(const float2*)&bJ[tx*4+r][dd];
    }
    #pragma unroll
    for (int ri = 0; ri < 4; ++ri)
      #pragma unroll
      for (int rj = 0; rj < 4; ++rj)
        acc[ri][rj] += av[ri].x*bv[rj].x + av[ri].y*bv[rj].y;
  }
  float dgv[4], sgv[4];
  #pragma unroll
  for (int r = 0; r < 4; ++r){
    dgv[r] = dg[head*S_LEN + i0 + ty*4 + r];
    sgv[r] = sg[head*S_LEN + j0 + tx*4 + r];
  }
  #pragma unroll
  for (int ri = 0; ri < 4; ++ri){
    int gi = i0 + ty*4 + ri;
    f32x4 st;
    #pragma unroll
    for (int rj = 0; rj < 4; ++rj){
      int gj = j0 + tx*4 + rj;
      float x = acc[ri][rj];
      float aff = (x > 0.f) ? exp2f(log2f(x)*(2.f/3.f)) : 0.f;
      aff *= dgv[ri]*sgv[rj];
      float ld = log1pf(-fminf(aff, 1.0f - 1e-6f));
      st[rj] = (gi > gj) ? ld : 0.f;
    }
    *(f32x4*)&Dm[((size_t)head*S_LEN + gi)*S_LEN + j0 + tx*4] = st;
  }
}

// ---------------- kernel 4a: chunk partial sums over i ----------------
__global__ __launch_bounds__(256) void k_scanA(const float* __restrict__ Dm,
                                               float* __restrict__ part){
  int cb    = blockIdx.x & 3;
  int chunk = (blockIdx.x >> 2) & 7;
  int head  = blockIdx.x >> 5;
  int j = cb*256 + threadIdx.x;
  const float* base = Dm + (size_t)head*S_LEN*S_LEN;
  float sum = 0.f;
  int ibeg = chunk*128;
  #pragma unroll 4
  for (int i = ibeg; i < ibeg + 128; ++i)
    if (i > j) sum += base[(size_t)i*S_LEN + j];
  part[(head*8 + chunk)*1024 + j] = sum;
}

// ---------------- kernel 4b: exclusive scan within chunk (in-place) ----------------
__global__ __launch_bounds__(256) void k_scanB(float* __restrict__ Dm,
                                               const float* __restrict__ part){
  int cb    = blockIdx.x & 3;
  int chunk = (blockIdx.x >> 2) & 7;
  int head  = blockIdx.x >> 5;
  int j = cb*256 + threadIdx.x;
  float run = 0.f;
  for (int c = 0; c < chunk; ++c) run += part[(head*8 + c)*1024 + j];
  float* base = Dm + (size_t)head*S_LEN*S_LEN;
  int ibeg = chunk*128;
  #pragma unroll 8
  for (int i = ibeg; i < ibeg + 128; ++i){
    size_t a = (size_t)i*S_LEN + j;
    float v = (i > j) ? base[a] : 0.f;
    base[a] = run;
    run += v;
  }
}

// ---------------- kernel 5: flash attention with decay bias (bf16 MFMA) ----------------
// Pipelined rewrite:
//  - K/V tiles double-buffered in LDS via global_load_lds (16B), shared by 4 waves
//  - linear LDS dest + inverse-XOR-swizzled global src + XOR-swizzled ds_read (chunk ^= row&7)
//  - D bias register-prefetched at iteration top (counted vmcnt keeps stage in flight)
//  - heavy tiles (it=15) launch first
//  - LDS = 16K + 16K + 8K = 40KB exactly -> 4 blocks/CU
__global__ __launch_bounds__(256, 4) void k_attn(const unsigned short* __restrict__ qb,
                                              const unsigned short* __restrict__ knb,
                                              const unsigned short* __restrict__ vT,
                                              const float* __restrict__ Dm,
                                              float* __restrict__ out){
  __shared__ unsigned short kts[2][4096];   // [buf][64 rows][64 cols] bf16, swizzled
  __shared__ unsigned short vts[2][4096];   // [buf][64 dd  ][64 j   ] bf16, swizzled
  __shared__ unsigned short plds[4096];     // [4 waves][16 rows][64 cols] bf16, swizzled

  int bh = blockIdx.x & 63;                 // b*32 + h
  int it = 15 - (blockIdx.x >> 6);          // heavy i-tiles first
  int h  = bh & 31;
  int head = (bh >> 5)*NHKV + (h >> 2);     // b*8 + h/4
  int w    = threadIdx.x >> 6;
  int lane = threadIdx.x & 63;
  int g16 = lane >> 4, l16 = lane & 15;
  int i0 = it*64 + w*16;                    // wave's first query row

  const unsigned short* Qp = qb  + ((size_t)bh*S_LEN + i0)*DH;
  const unsigned short* Kp = knb + (size_t)head*S_LEN*DH;
  const unsigned short* Vp = vT  + (size_t)head*DH*S_LEN;
  const float*          Dp = Dm  + ((size_t)head*S_LEN + i0)*S_LEN;

  // --- staging addressing (elements). chunk c in 0..7, wave w stages c=w and c=w+4.
  // lane covers row r = c*8 + (lane>>3), 16B sub-chunk ci = lane&7, source pre-swizzled:
  // LDS[r][ci] = global[r][ci ^ (r&7)]  (r&7 == lane>>3 inside a chunk)
  int rsub = lane >> 3;
  int cisw = ((lane & 7) ^ rsub) * 8;
  int kg0 = (w*8 + rsub)*64   + cisw;       // K: row stride 64 elements
  int kg1 = ((w+4)*8 + rsub)*64 + cisw;
  int vg0 = (w*8 + rsub)*1024 + cisw;       // V: row stride S_LEN elements
  int vg1 = ((w+4)*8 + rsub)*1024 + cisw;
  int kl0 = w*512;                          // wave-uniform LDS chunk bases (elements)
  int kl1 = (w+4)*512;

  // --- fragment read offsets (elements), same for K, V, and P tiles:
  // row = n*16+l16, want global chunk kk*4+g16 -> read swizzled chunk (kk*4+g16)^(l16&7)
  int c0 = g16 ^ (l16 & 7);
  int e0 = l16*64 + c0*8;                   // kk = 0
  int e1 = l16*64 + (c0 ^ 4)*8;             // kk = 1

  bf16x8 aq[2];
  aq[0] = *(const bf16x8*)(Qp + (size_t)l16*DH + g16*8);
  aq[1] = *(const bf16x8*)(Qp + (size_t)l16*DH + 32 + g16*8);

  f32x4 oacc[4];
  float m[4], ssum[4];
  #pragma unroll
  for (int n = 0; n < 4; ++n) oacc[n] = (f32x4){0.f,0.f,0.f,0.f};
  #pragma unroll
  for (int r = 0; r < 4; ++r){ m[r] = -INFINITY; ssum[r] = 0.f; }

  auto STAGE = [&](int b, int jtile){
    const unsigned short* ks = Kp + (size_t)jtile*(64*DH);
    const unsigned short* vs = Vp + (size_t)jtile*64;
    gload16(ks + kg0, &kts[b][kl0]);
    gload16(ks + kg1, &kts[b][kl1]);
    gload16(vs + vg0, &vts[b][kl0]);
    gload16(vs + vg1, &vts[b][kl1]);
  };

  int hi = l16 >> 3, lo = l16 & 7;
  unsigned short* pw = plds + w*1024;

  // prologue: stage tile 0
  STAGE(0, 0);
  __syncthreads();

  int cur = 0;
  for (int jt = 0; jt <= it; ++jt){
    // D bias prefetch for CURRENT tile (issued before stage -> auto-counted vmcnt
    // lets the 4 stage ops stay in flight when these are consumed)
    float dv[4][4];
    {
      const float* dcol = Dp + jt*64 + l16;
      #pragma unroll
      for (int n = 0; n < 4; ++n)
        #pragma unroll
        for (int r = 0; r < 4; ++r)
          dv[n][r] = dcol[(size_t)(g16*4 + r)*S_LEN + n*16];
    }
    // prefetch next K/V tile into the other buffer
    if (jt < it) STAGE(cur ^ 1, jt + 1);

    const unsigned short* kcur = &kts[cur][0];
    const unsigned short* vcur = &vts[cur][0];

    // QK^T from LDS (swizzled ds_read_b128)
    f32x4 sc[4];
    #pragma unroll
    for (int n = 0; n < 4; ++n) sc[n] = (f32x4){0.f,0.f,0.f,0.f};
    #pragma unroll
    for (int n = 0; n < 4; ++n){
      bf16x8 bk = *(const bf16x8*)(kcur + n*1024 + e0);
      sc[n] = __builtin_amdgcn_mfma_f32_16x16x32_bf16(aq[0], bk, sc[n], 0, 0, 0);
    }
    #pragma unroll
    for (int n = 0; n < 4; ++n){
      bf16x8 bk = *(const bf16x8*)(kcur + n*1024 + e1);
      sc[n] = __builtin_amdgcn_mfma_f32_16x16x32_bf16(aq[1], bk, sc[n], 0, 0, 0);
    }

    // decay bias; causal mask only needed on the diagonal tile
    if (jt == it){
      #pragma unroll
      for (int n = 0; n < 4; ++n)
        #pragma unroll
        for (int r = 0; r < 4; ++r){
          int row = g16*4 + r;
          int col = n*16 + l16;
          sc[n][r] = (col <= w*16 + row) ? (sc[n][r] + dv[n][r]) : NEG_INF;
        }
    } else {
      #pragma unroll
      for (int n = 0; n < 4; ++n)
        #pragma unroll
        for (int r = 0; r < 4; ++r)
          sc[n][r] += dv[n][r];
    }

    // online softmax (rows live across 16-lane groups)
    float mx[4];
    #pragma unroll
    for (int r = 0; r < 4; ++r)
      mx[r] = fmaxf(fmaxf(sc[0][r], sc[1][r]), fmaxf(sc[2][r], sc[3][r]));
    #pragma unroll
    for (int off = 8; off >= 1; off >>= 1)
      #pragma unroll
      for (int r = 0; r < 4; ++r)
        mx[r] = fmaxf(mx[r], __shfl_xor(mx[r], off));
    float scale[4];
    #pragma unroll
    for (int r = 0; r < 4; ++r){
      float mn = fmaxf(m[r], mx[r]);
      scale[r] = __expf(m[r] - mn);
      m[r] = mn;
    }
    float ps[4] = {0.f,0.f,0.f,0.f};
    #pragma unroll
    for (int n = 0; n < 4; ++n){
      #pragma unroll
      for (int r = 0; r < 4; ++r){
        float p = __expf(sc[n][r] - m[r]);
        ps[r] += p;
        int row = g16*4 + r;
        // swizzled P store: element col = n*16+l16 -> chunk (2n|hi) ^ (row&7), sub lo
        pw[row*64 + (((2*n + hi) ^ (row & 7))*8) + lo] = f2bf(p);
      }
    }
    #pragma unroll
    for (int r = 0; r < 4; ++r) ssum[r] = ssum[r]*scale[r] + ps[r];
    #pragma unroll
    for (int n = 0; n < 4; ++n)
      #pragma unroll
      for (int r = 0; r < 4; ++r) oacc[n][r] *= scale[r];

    // PV from LDS (P and V both swizzle-read with e0/e1)
    {
      bf16x8 pa0 = *(const bf16x8*)(pw + e0);
      #pragma unroll
      for (int n = 0; n < 4; ++n){
        bf16x8 bv = *(const bf16x8*)(vcur + n*1024 + e0);
        oacc[n] = __builtin_amdgcn_mfma_f32_16x16x32_bf16(pa0, bv, oacc[n], 0, 0, 0);
      }
      bf16x8 pa1 = *(const bf16x8*)(pw + e1);
      #pragma unroll
      for (int n = 0; n < 4; ++n){
        bf16x8 bv = *(const bf16x8*)(vcur + n*1024 + e1);
        oacc[n] = __builtin_amdgcn_mfma_f32_16x16x32_bf16(pa1, bv, oacc[n], 0, 0, 0);
      }
    }

    __syncthreads();   // drains stage vmcnt (compiler emits waitcnt) + swaps buffers safely
    cur ^= 1;
  }

  // epilogue
  #pragma unroll
  for (int off = 8; off >= 1; off >>= 1)
    #pragma unroll
    for (int r = 0; r < 4; ++r) ssum[r] += __shfl_xor(ssum[r], off);
  float* Op = out + ((size_t)bh*S_LEN + i0)*DH;
  #pragma unroll
  for (int n = 0; n < 4; ++n)
    #pragma unroll
    for (int r = 0; r < 4; ++r)
      Op[(size_t)(g16*4 + r)*DH + n*16 + l16] = oacc[n][r] / ssum[r];
}

extern "C" void kernel_launch(void* const* d_in, const int* in_sizes, int n_in,
                              void* d_out, int out_size, void* d_ws, size_t ws_size,
                              hipStream_t stream){
  const float* q    = (const float*)d_in[0];
  const float* k    = (const float*)d_in[1];
  const float* v    = (const float*)d_in[2];
  const float* src  = (const float*)d_in[3];
  const float* dest = (const float*)d_in[4];
  float* out = (float*)d_out;

  char* w = (char*)d_ws;
  float*          kn   = (float*)w;                                  // 4 MB
  float*          Dm   = (float*)(w + (size_t)(4u  << 20));          // 64 MB
  unsigned short* qb   = (unsigned short*)(w + (size_t)(68u << 20)); // 8 MB
  unsigned short* knb  = (unsigned short*)(w + (size_t)(76u << 20)); // 2 MB
  unsigned short* vT   = (unsigned short*)(w + (size_t)(78u << 20)); // 2 MB
  float*          dg   = (float*)(w + (size_t)(80u << 20));          // 64 KB
  float*          sg   = (float*)(w + (size_t)(80u << 20) + 65536);  // 64 KB
  float*          part = (float*)(w + (size_t)(80u << 20) + 131072); // 512 KB

  k_prep_kn  <<<dim3(NHEADS*S_LEN/4), dim3(256), 0, stream>>>(k, kn, knb);
  k_prep_misc<<<dim3(NB*NHQ*S_LEN*DH/256), dim3(256), 0, stream>>>(q, v, src, dest, qb, vT, sg, dg);
  k_logdec   <<<dim3(NHEADS*NTRI), dim3(256), 0, stream>>>(kn, dg, sg, Dm);
  k_scanA    <<<dim3(NHEADS*8*4), dim3(256), 0, stream>>>(Dm, part);
  k_scanB    <<<dim3(NHEADS*8*4), dim3(256), 0, stream>>>(Dm, part);
  k_attn     <<<dim3(NB*NHQ*NTILE), dim3(256), 0, stream>>>(qb, knb, vT, Dm, out);
}

// Round 2
// 132.112 us; speedup vs baseline: 2.4411x; 1.6177x over previous
//
#include <hip/hip_runtime.h>
#include <hip/hip_bf16.h>
#include <math.h>

#define S_LEN 1024
#define DH 64
#define NB 2
#define NHQ 32
#define NHKV 8
#define NHEADS (NB*NHKV)      // 16 kv-head planes
#define NTILE 16              // S/64
#define NTRI 136              // 16*17/2 lower-tri tiles
#define NEG_INF -1e30f

using bf16x8 = __attribute__((ext_vector_type(8))) __bf16;
using f32x4  = __attribute__((ext_vector_type(4))) float;

__device__ inline unsigned short f2bf(float f){
  unsigned int u = __float_as_uint(f);
  unsigned int r = (u + 0x7FFFu + ((u >> 16) & 1u)) >> 16;
  return (unsigned short)r;
}

// async global->LDS, 16B per lane, wave-uniform LDS base + lane*16
__device__ inline void gload16(const void* g, void* l){
  __builtin_amdgcn_global_load_lds(
      (const __attribute__((address_space(1))) void*)g,
      (__attribute__((address_space(3))) void*)l, 16, 0, 0);
}

// ---------------- kernel 1: normalize k rows -> knb (bf16 hi) + knl (bf16 lo) ----------------
__global__ __launch_bounds__(256) void k_prep_kn(const float* __restrict__ k,
                                                 unsigned short* __restrict__ knb,
                                                 unsigned short* __restrict__ knl){
  int row  = blockIdx.x*4 + (threadIdx.x >> 6);   // among NHEADS*S
  int lane = threadIdx.x & 63;
  size_t idx = (size_t)row*DH + lane;
  float x = k[idx];
  float ss = x*x;
  #pragma unroll
  for (int off = 32; off > 0; off >>= 1) ss += __shfl_xor(ss, off);
  float r = x / (sqrtf(ss) + 1e-6f);
  unsigned short h = f2bf(r);
  float hf = __uint_as_float((unsigned int)h << 16);
  knb[idx] = h;
  knl[idx] = f2bf(r - hf);
}

// ---------------- kernel 2: q->bf16, v->vT bf16, gates ----------------
__global__ __launch_bounds__(256) void k_prep_misc(const float* __restrict__ q,
                                                   const float* __restrict__ v,
                                                   const float* __restrict__ src,
                                                   const float* __restrict__ dest,
                                                   unsigned short* __restrict__ qb,
                                                   unsigned short* __restrict__ vT,
                                                   float* __restrict__ sg,
                                                   float* __restrict__ dg){
  int idx = blockIdx.x*256 + threadIdx.x;          // grid covers exactly B*H*S*D = 4M
  qb[idx] = f2bf(q[idx]);
  if (idx < NHEADS*DH*S_LEN){                      // 1M : vT[bh][dd][j] = v[bh][j][dd]
    int bh  = idx >> 16;
    int rem = idx & 65535;
    int dd  = rem >> 10;
    int j   = rem & 1023;
    vT[idx] = f2bf(v[((size_t)bh << 16) + (size_t)j*DH + dd]);
  }
  if (idx < 2*NHEADS*S_LEN){                       // 32768 : gates
    if (idx < NHEADS*S_LEN){
      float s = 1.f/(1.f + __expf(-dest[idx]));
      dg[idx] = (s > 0.f) ? exp2f(log2f(s)*(1.f/3.f)) : 0.f;
    } else {
      int i2 = idx - NHEADS*S_LEN;
      float s = 1.f/(1.f + __expf(-src[i2]));
      sg[i2] = (s > 0.f) ? exp2f(log2f(s)*(1.f/3.f)) : 0.f;
    }
  }
}

// ---------------- kernel 3: logdec tiles via bf16 hi/lo MFMA + fused in-tile scan ----------
// dot = hh + hl + lh (fp32 MFMA accumulate) -> ~2^-16 relative accuracy.
// Writes Dm'[head][i][j] = exclusive column cumsum WITHIN the 64-row i-tile,
// and T[head][ti][j]   = full column sum of the tile (for cross-tile prefix).
__global__ __launch_bounds__(256) void k_logdec(const unsigned short* __restrict__ knh,
                                                const unsigned short* __restrict__ knl,
                                                const float* __restrict__ dg,
                                                const float* __restrict__ sg,
                                                float* __restrict__ Dm,
                                                float* __restrict__ T){
  __shared__ float wsum[4][4][16];   // [wave][n][l16] column totals
  int head = blockIdx.x / NTRI;
  int t    = blockIdx.x % NTRI;
  int ti = 0;
  while ((ti+1)*(ti+2)/2 <= t) ti++;
  int tj = t - ti*(ti+1)/2;
  int i0 = ti*64, j0 = tj*64;
  const unsigned short* Hp = knh + (size_t)head*S_LEN*DH;
  const unsigned short* Lp = knl + (size_t)head*S_LEN*DH;
  int w = threadIdx.x >> 6, lane = threadIdx.x & 63;
  int g16 = lane >> 4, l16 = lane & 15;

  // A fragments: I-rows w*16 + l16
  bf16x8 ah[2], al[2];
  {
    size_t ro = (size_t)(i0 + w*16 + l16)*DH + g16*8;
    ah[0] = *(const bf16x8*)(Hp + ro);
    ah[1] = *(const bf16x8*)(Hp + ro + 32);
    al[0] = *(const bf16x8*)(Lp + ro);
    al[1] = *(const bf16x8*)(Lp + ro + 32);
  }

  f32x4 sc[4];
  #pragma unroll
  for (int n = 0; n < 4; ++n) sc[n] = (f32x4){0.f,0.f,0.f,0.f};
  #pragma unroll
  for (int n = 0; n < 4; ++n){
    size_t ro = (size_t)(j0 + n*16 + l16)*DH + g16*8;
    #pragma unroll
    for (int kk = 0; kk < 2; ++kk){
      bf16x8 bh_ = *(const bf16x8*)(Hp + ro + kk*32);
      bf16x8 bl_ = *(const bf16x8*)(Lp + ro + kk*32);
      sc[n] = __builtin_amdgcn_mfma_f32_16x16x32_bf16(ah[kk], bh_, sc[n], 0, 0, 0);
      sc[n] = __builtin_amdgcn_mfma_f32_16x16x32_bf16(ah[kk], bl_, sc[n], 0, 0, 0);
      sc[n] = __builtin_amdgcn_mfma_f32_16x16x32_bf16(al[kk], bh_, sc[n], 0, 0, 0);
    }
  }

  // gates: out row (in tile) = w*16 + g16*4 + r ; col = n*16 + l16
  float dgv[4], sgv[4];
  #pragma unroll
  for (int r = 0; r < 4; ++r) dgv[r] = dg[head*S_LEN + i0 + w*16 + g16*4 + r];
  #pragma unroll
  for (int n = 0; n < 4; ++n) sgv[n] = sg[head*S_LEN + j0 + n*16 + l16];

  // per-element logdec with strict mask
  float ldv[4][4];   // [n][r]
  #pragma unroll
  for (int n = 0; n < 4; ++n)
    #pragma unroll
    for (int r = 0; r < 4; ++r){
      int gi = i0 + w*16 + g16*4 + r;
      int gj = j0 + n*16 + l16;
      float x = sc[n][r];
      float aff = (x > 0.f) ? exp2f(log2f(x)*(2.f/3.f)) : 0.f;
      aff *= dgv[r]*sgv[n];
      float ld = log1pf(-fminf(aff, 1.0f - 1e-6f));
      ldv[n][r] = (gi > gj) ? ld : 0.f;
    }

  // column-wise exclusive cumsum over the 64 tile rows
  float pre[4][4], tot[4];
  #pragma unroll
  for (int n = 0; n < 4; ++n){
    float s = 0.f;
    #pragma unroll
    for (int r = 0; r < 4; ++r){ pre[n][r] = s; s += ldv[n][r]; }
    tot[n] = s;
  }
  float offg[4], wt[4];
  #pragma unroll
  for (int n = 0; n < 4; ++n){
    float t0 = __shfl(tot[n], l16);
    float t1 = __shfl(tot[n], 16 + l16);
    float t2 = __shfl(tot[n], 32 + l16);
    float t3 = __shfl(tot[n], 48 + l16);
    offg[n] = (g16 > 0 ? t0 : 0.f) + (g16 > 1 ? t1 : 0.f) + (g16 > 2 ? t2 : 0.f);
    wt[n]   = t0 + t1 + t2 + t3;
  }
  // wave totals -> LDS (lane writes n == its g16, static select to avoid scratch)
  float sel = (g16 == 0) ? wt[0] : (g16 == 1) ? wt[1] : (g16 == 2) ? wt[2] : wt[3];
  wsum[w][g16][l16] = sel;
  __syncthreads();
  float offW[4];
  #pragma unroll
  for (int n = 0; n < 4; ++n){
    float a0 = wsum[0][n][l16], a1 = wsum[1][n][l16], a2 = wsum[2][n][l16];
    offW[n] = (w > 0 ? a0 : 0.f) + (w > 1 ? a1 : 0.f) + (w > 2 ? a2 : 0.f);
  }
  // tile column totals (wave 0 writes; col = g16*16 + l16)
  if (w == 0){
    float colt = wsum[0][g16][l16] + wsum[1][g16][l16] + wsum[2][g16][l16] + wsum[3][g16][l16];
    T[((size_t)head*NTILE + ti)*S_LEN + j0 + g16*16 + l16] = colt;
  }
  // store within-tile exclusive cumsum
  #pragma unroll
  for (int n = 0; n < 4; ++n)
    #pragma unroll
    for (int r = 0; r < 4; ++r){
      int gi = i0 + w*16 + g16*4 + r;
      int gj = j0 + n*16 + l16;
      Dm[((size_t)head*S_LEN + gi)*S_LEN + gj] = offW[n] + offg[n] + pre[n][r];
    }
}

// ---------------- kernel 4: cross-tile column prefix  Cpre[head][it][j] ----------------
__global__ __launch_bounds__(256) void k_cpre(const float* __restrict__ T,
                                              float* __restrict__ Cpre){
  int g = blockIdx.x*256 + threadIdx.x;   // over NHEADS*S_LEN
  int head = g >> 10, jj = g & 1023;
  int tjcol = jj >> 6;
  float run = 0.f;
  #pragma unroll
  for (int it = 0; it < NTILE; ++it){
    Cpre[((size_t)head*NTILE + it)*S_LEN + jj] = run;
    if (it >= tjcol) run += T[((size_t)head*NTILE + it)*S_LEN + jj];
  }
}

// ---------------- kernel 5: flash attention with decay bias (bf16 MFMA) ----------------
__global__ __launch_bounds__(256, 4) void k_attn(const unsigned short* __restrict__ qb,
                                              const unsigned short* __restrict__ knb,
                                              const unsigned short* __restrict__ vT,
                                              const float* __restrict__ Dm,
                                              const float* __restrict__ Cpre,
                                              float* __restrict__ out){
  __shared__ unsigned short kts[2][4096];   // [buf][64 rows][64 cols] bf16, swizzled
  __shared__ unsigned short vts[2][4096];   // [buf][64 dd  ][64 j   ] bf16, swizzled
  __shared__ unsigned short plds[4096];     // [4 waves][16 rows][64 cols] bf16, swizzled

  int bh = blockIdx.x & 63;                 // b*32 + h
  int it = 15 - (blockIdx.x >> 6);          // heavy i-tiles first
  int h  = bh & 31;
  int head = (bh >> 5)*NHKV + (h >> 2);     // b*8 + h/4
  int w    = threadIdx.x >> 6;
  int lane = threadIdx.x & 63;
  int g16 = lane >> 4, l16 = lane & 15;
  int i0 = it*64 + w*16;                    // wave's first query row

  const unsigned short* Qp = qb  + ((size_t)bh*S_LEN + i0)*DH;
  const unsigned short* Kp = knb + (size_t)head*S_LEN*DH;
  const unsigned short* Vp = vT  + (size_t)head*DH*S_LEN;
  const float*          Dp = Dm  + ((size_t)head*S_LEN + i0)*S_LEN;
  const float*          Cp = Cpre + ((size_t)head*NTILE + it)*S_LEN;

  // staging addressing (see round-1 comments): linear LDS dest + inverse-swizzled src
  int rsub = lane >> 3;
  int cisw = ((lane & 7) ^ rsub) * 8;
  int kg0 = (w*8 + rsub)*64   + cisw;
  int kg1 = ((w+4)*8 + rsub)*64 + cisw;
  int vg0 = (w*8 + rsub)*1024 + cisw;
  int vg1 = ((w+4)*8 + rsub)*1024 + cisw;
  int kl0 = w*512;
  int kl1 = (w+4)*512;

  // fragment read offsets: row = n*16+l16, chunk (kk*4+g16)^(l16&7)
  int c0 = g16 ^ (l16 & 7);
  int e0 = l16*64 + c0*8;
  int e1 = l16*64 + (c0 ^ 4)*8;

  bf16x8 aq[2];
  aq[0] = *(const bf16x8*)(Qp + (size_t)l16*DH + g16*8);
  aq[1] = *(const bf16x8*)(Qp + (size_t)l16*DH + 32 + g16*8);

  f32x4 oacc[4];
  float m[4], ssum[4];
  #pragma unroll
  for (int n = 0; n < 4; ++n) oacc[n] = (f32x4){0.f,0.f,0.f,0.f};
  #pragma unroll
  for (int r = 0; r < 4; ++r){ m[r] = -INFINITY; ssum[r] = 0.f; }

  auto STAGE = [&](int b, int jtile){
    const unsigned short* ks = Kp + (size_t)jtile*(64*DH);
    const unsigned short* vs = Vp + (size_t)jtile*64;
    gload16(ks + kg0, &kts[b][kl0]);
    gload16(ks + kg1, &kts[b][kl1]);
    gload16(vs + vg0, &vts[b][kl0]);
    gload16(vs + vg1, &vts[b][kl1]);
  };

  int hi = l16 >> 3, lo = l16 & 7;
  unsigned short* pw = plds + w*1024;

  STAGE(0, 0);
  __syncthreads();

  int cur = 0;
  for (int jt = 0; jt <= it; ++jt){
    // D bias + cross-tile prefix prefetch for CURRENT tile
    float dv[4][4];
    float cp[4];
    {
      const float* dcol = Dp + jt*64 + l16;
      #pragma unroll
      for (int n = 0; n < 4; ++n){
        cp[n] = Cp[jt*64 + n*16 + l16];
        #pragma unroll
        for (int r = 0; r < 4; ++r)
          dv[n][r] = dcol[(size_t)(g16*4 + r)*S_LEN + n*16];
      }
    }
    if (jt < it) STAGE(cur ^ 1, jt + 1);

    const unsigned short* kcur = &kts[cur][0];
    const unsigned short* vcur = &vts[cur][0];

    f32x4 sc[4];
    #pragma unroll
    for (int n = 0; n < 4; ++n) sc[n] = (f32x4){0.f,0.f,0.f,0.f};
    #pragma unroll
    for (int n = 0; n < 4; ++n){
      bf16x8 bk = *(const bf16x8*)(kcur + n*1024 + e0);
      sc[n] = __builtin_amdgcn_mfma_f32_16x16x32_bf16(aq[0], bk, sc[n], 0, 0, 0);
    }
    #pragma unroll
    for (int n = 0; n < 4; ++n){
      bf16x8 bk = *(const bf16x8*)(kcur + n*1024 + e1);
      sc[n] = __builtin_amdgcn_mfma_f32_16x16x32_bf16(aq[1], bk, sc[n], 0, 0, 0);
    }

    if (jt == it){
      #pragma unroll
      for (int n = 0; n < 4; ++n)
        #pragma unroll
        for (int r = 0; r < 4; ++r){
          int row = g16*4 + r;
          int col = n*16 + l16;
          sc[n][r] = (col <= w*16 + row) ? (sc[n][r] + dv[n][r] + cp[n]) : NEG_INF;
        }
    } else {
      #pragma unroll
      for (int n = 0; n < 4; ++n)
        #pragma unroll
        for (int r = 0; r < 4; ++r)
          sc[n][r] += dv[n][r] + cp[n];
    }

    float mx[4];
    #pragma unroll
    for (int r = 0; r < 4; ++r)
      mx[r] = fmaxf(fmaxf(sc[0][r], sc[1][r]), fmaxf(sc[2][r], sc[3][r]));
    #pragma unroll
    for (int off = 8; off >= 1; off >>= 1)
      #pragma unroll
      for (int r = 0; r < 4; ++r)
        mx[r] = fmaxf(mx[r], __shfl_xor(mx[r], off));
    float scale[4];
    #pragma unroll
    for (int r = 0; r < 4; ++r){
      float mn = fmaxf(m[r], mx[r]);
      scale[r] = __expf(m[r] - mn);
      m[r] = mn;
    }
    float ps[4] = {0.f,0.f,0.f,0.f};
    #pragma unroll
    for (int n = 0; n < 4; ++n){
      #pragma unroll
      for (int r = 0; r < 4; ++r){
        float p = __expf(sc[n][r] - m[r]);
        ps[r] += p;
        int row = g16*4 + r;
        pw[row*64 + (((2*n + hi) ^ (row & 7))*8) + lo] = f2bf(p);
      }
    }
    #pragma unroll
    for (int r = 0; r < 4; ++r) ssum[r] = ssum[r]*scale[r] + ps[r];
    #pragma unroll
    for (int n = 0; n < 4; ++n)
      #pragma unroll
      for (int r = 0; r < 4; ++r) oacc[n][r] *= scale[r];

    {
      bf16x8 pa0 = *(const bf16x8*)(pw + e0);
      #pragma unroll
      for (int n = 0; n < 4; ++n){
        bf16x8 bv = *(const bf16x8*)(vcur + n*1024 + e0);
        oacc[n] = __builtin_amdgcn_mfma_f32_16x16x32_bf16(pa0, bv, oacc[n], 0, 0, 0);
      }
      bf16x8 pa1 = *(const bf16x8*)(pw + e1);
      #pragma unroll
      for (int n = 0; n < 4; ++n){
        bf16x8 bv = *(const bf16x8*)(vcur + n*1024 + e1);
        oacc[n] = __builtin_amdgcn_mfma_f32_16x16x32_bf16(pa1, bv, oacc[n], 0, 0, 0);
      }
    }

    __syncthreads();
    cur ^= 1;
  }

  #pragma unroll
  for (int off = 8; off >= 1; off >>= 1)
    #pragma unroll
    for (int r = 0; r < 4; ++r) ssum[r] += __shfl_xor(ssum[r], off);
  float* Op = out + ((size_t)bh*S_LEN + i0)*DH;
  #pragma unroll
  for (int n = 0; n < 4; ++n)
    #pragma unroll
    for (int r = 0; r < 4; ++r)
      Op[(size_t)(g16*4 + r)*DH + n*16 + l16] = oacc[n][r] / ssum[r];
}

extern "C" void kernel_launch(void* const* d_in, const int* in_sizes, int n_in,
                              void* d_out, int out_size, void* d_ws, size_t ws_size,
                              hipStream_t stream){
  const float* q    = (const float*)d_in[0];
  const float* k    = (const float*)d_in[1];
  const float* v    = (const float*)d_in[2];
  const float* src  = (const float*)d_in[3];
  const float* dest = (const float*)d_in[4];
  float* out = (float*)d_out;

  char* w = (char*)d_ws;
  float*          Dm   = (float*)w;                                   // 64 MB
  unsigned short* qb   = (unsigned short*)(w + (size_t)(64u << 20));  // 8 MB
  unsigned short* knb  = (unsigned short*)(w + (size_t)(72u << 20));  // 2 MB
  unsigned short* knl  = (unsigned short*)(w + (size_t)(74u << 20));  // 2 MB
  unsigned short* vT   = (unsigned short*)(w + (size_t)(76u << 20));  // 2 MB
  float*          dg   = (float*)(w + (size_t)(78u << 20));           // 64 KB
  float*          sg   = (float*)(w + (size_t)(78u << 20) + 65536);   // 64 KB
  float*          T    = (float*)(w + (size_t)(78u << 20) + 131072);  // 1 MB
  float*          Cpre = (float*)(w + (size_t)(78u << 20) + 131072 + (size_t)(1u << 20)); // 1 MB

  k_prep_kn  <<<dim3(NHEADS*S_LEN/4), dim3(256), 0, stream>>>(k, knb, knl);
  k_prep_misc<<<dim3(NB*NHQ*S_LEN*DH/256), dim3(256), 0, stream>>>(q, v, src, dest, qb, vT, sg, dg);
  k_logdec   <<<dim3(NHEADS*NTRI), dim3(256), 0, stream>>>(knb, knl, dg, sg, Dm, T);
  k_cpre     <<<dim3(NHEADS*S_LEN/256), dim3(256), 0, stream>>>(T, Cpre);
  k_attn     <<<dim3(NB*NHQ*NTILE), dim3(256), 0, stream>>>(qb, knb, vT, Dm, Cpre, out);
}